// Round 7
// baseline (149.712 us; speedup 1.0000x reference)
//
#include <hip/hip_runtime.h>
#include <hip/hip_bf16.h>

#define BATCH 8
#define CH    64
#define NPIX  65536
#define NHEAD 2
#define HDIM  32
#define P1_BLOCKS 128  // pass-1 blocks per batch; each does 4 tiles of 128 px

typedef __attribute__((ext_vector_type(8))) short bf16x8;
typedef __attribute__((ext_vector_type(4))) float f32x4;

#define MFMA(a, b, c) __builtin_amdgcn_mfma_f32_16x16x32_bf16(a, b, c, 0, 0, 0)

// pack two f32 -> one u32 holding two bf16 (RNE)
__device__ __forceinline__ unsigned rne_pk(float lo, float hi) {
    unsigned ua = __float_as_uint(lo); ua += 0x7fffu + ((ua >> 16) & 1u);
    unsigned ub = __float_as_uint(hi); ub += 0x7fffu + ((ub >> 16) & 1u);
    return (ua >> 16) | (ub & 0xffff0000u);
}

__device__ __forceinline__ bf16x8 pack8(const float* f) {
    int4 iv;
    iv.x = (int)rne_pk(f[0], f[1]);
    iv.y = (int)rne_pk(f[2], f[3]);
    iv.z = (int)rne_pk(f[4], f[5]);
    iv.w = (int)rne_pk(f[6], f[7]);
    return *reinterpret_cast<bf16x8*>(&iv);
}

__device__ __forceinline__ float phi_f(float t) {
    return t > 0.0f ? t + 1.0f : __expf(t);
}

// 8 bf16 from LDS at 8B alignment (two b64 reads)
__device__ __forceinline__ bf16x8 lds_read8(const unsigned short* p) {
    uint2 a = *reinterpret_cast<const uint2*>(p);
    uint2 b = *reinterpret_cast<const uint2*>(p + 4);
    int4 iv; iv.x = (int)a.x; iv.y = (int)a.y; iv.z = (int)b.x; iv.w = (int)b.y;
    return *reinterpret_cast<bf16x8*>(&iv);
}

// A-layout fragment of row-major W[*][64]: lane gets (m = r0+l%16, k = k0+(l/16)*8+e)
__device__ __forceinline__ bf16x8 load_w_frag(const float* W, int r0, int k0, int lane) {
    const float* p = W + (size_t)(r0 + (lane & 15)) * 64 + k0 + ((lane >> 4) << 3);
    float f[8];
    #pragma unroll
    for (int e = 0; e < 8; e++) f[e] = p[e];
    return pack8(f);
}

// ---------------- Pass 1: coalesced x stage -> LDS transpose -> MFMA; partial KV + xt ----------------
// grid (P1_BLOCKS, 8), block 256 (4 waves). Per iter: block stages 128px x 64ch of x
// with pixel-major float4 streams (no strided global gather), then each wave MFMAs its 32-px strip.
__global__ __launch_bounds__(256) void la_pass1(
    const float* __restrict__ x, const float* __restrict__ qkv_w,
    float* __restrict__ partials, unsigned short* __restrict__ xt)
{
    // 16384B xls + 4 waves * 2 bufs * 64*36*2B = 52KB total -> 3 blocks/CU
    __shared__ __align__(16) unsigned char smem[53248];
    unsigned short* xls = (unsigned short*)smem;                       // [64][128] bf16

    const int tid  = threadIdx.x;
    const int lane = tid & 63;
    const int wv   = __builtin_amdgcn_readfirstlane(tid >> 6);
    const int b    = blockIdx.y;
    const int g    = lane >> 4;      // 0..3
    const int li   = lane & 15;
    const int l32  = lane & 31;
    const int lhi  = lane >> 5;      // 0/1

    unsigned short* kls = (unsigned short*)(smem + 16384 + wv * 9216); // [64][36] bf16
    unsigned short* vls = kls + 64 * 36;

    // preload W^T B-frags for k|v output channels (qkv_w rows 64..191)
    bf16x8 Wf[8][2];
    #pragma unroll
    for (int j = 0; j < 8; j++)
        #pragma unroll
        for (int ks = 0; ks < 2; ks++)
            Wf[j][ks] = load_w_frag(qkv_w, 64 + 16 * j, 32 * ks, lane);

    f32x4 kvacc[2][2][2];  // [head][c-tile][d-tile]
    #pragma unroll
    for (int h = 0; h < 2; h++)
        #pragma unroll
        for (int mt = 0; mt < 2; mt++)
            #pragma unroll
            for (int nt = 0; nt < 2; nt++)
                kvacc[h][mt][nt] = (f32x4){0.f, 0.f, 0.f, 0.f};

    const float* xb = x + (size_t)b * CH * NPIX;
    unsigned short* xtb = xt + (size_t)b * NPIX * CH;

    for (int it = 0; it < 4; it++) {
        const int px0 = (blockIdx.x * 4 + it) * 128;

        // ---- stage: pixel-major coalesced float4 reads; bf16 pack; xls[ch][128]
        // instr j: wave covers channels {16wv+2j, 16wv+2j+1}, 128 px each (two 512B runs)
        #pragma unroll
        for (int j = 0; j < 8; j++) {
            const int ch = wv * 16 + 2 * j + lhi;
            const float4 f = *reinterpret_cast<const float4*>(
                xb + (size_t)ch * NPIX + px0 + 4 * l32);
            *reinterpret_cast<uint2*>(&xls[ch * 128 + 4 * l32]) =
                make_uint2(rne_pk(f.x, f.y), rne_pk(f.z, f.w));
        }
        __syncthreads();

        // ---- gather A-frags of X^T from xls: (m = px = 32wv+16mt+li, k = ch = 32ks+8g+e)
        bf16x8 xa[2][2];
        #pragma unroll
        for (int mt = 0; mt < 2; mt++) {
            const int px = 32 * wv + 16 * mt + li;
            #pragma unroll
            for (int ks = 0; ks < 2; ks++) {
                const unsigned short* sp = &xls[(32 * ks + 8 * g) * 128 + px];
                int4 iv;
                {
                    unsigned v0 = sp[0], v1 = sp[128], v2 = sp[256], v3 = sp[384];
                    unsigned v4 = sp[512], v5 = sp[640], v6 = sp[768], v7 = sp[896];
                    iv.x = (int)(v0 | (v1 << 16));
                    iv.y = (int)(v2 | (v3 << 16));
                    iv.z = (int)(v4 | (v5 << 16));
                    iv.w = (int)(v6 | (v7 << 16));
                }
                xa[mt][ks] = *reinterpret_cast<bf16x8*>(&iv);
            }
        }

        // ---- side-product: bf16 x^T[px][ch] for pass2 (b128, 2KB-contiguous per instr)
        #pragma unroll
        for (int mt = 0; mt < 2; mt++) {
            const int px = px0 + 32 * wv + 16 * mt + li;
            #pragma unroll
            for (int ks = 0; ks < 2; ks++)
                *reinterpret_cast<int4*>(xtb + (size_t)px * CH + 32 * ks + 8 * g) =
                    *reinterpret_cast<const int4*>(&xa[mt][ks]);
        }

        // ---- GEMM1: (K|V)^T tiles = X^T * W^T; write packed [c][px] bf16 to kls/vls
        #pragma unroll
        for (int j = 0; j < 8; j++) {
            unsigned short* dst = (j < 4) ? kls : vls;
            const int crow = (j & 3) * 16 + li;
            #pragma unroll
            for (int mt = 0; mt < 2; mt++) {
                f32x4 acc = (f32x4){0.f, 0.f, 0.f, 0.f};
                acc = MFMA(xa[mt][0], Wf[j][0], acc);
                acc = MFMA(xa[mt][1], Wf[j][1], acc);
                float v0 = acc[0], v1 = acc[1], v2 = acc[2], v3 = acc[3];
                if (j < 4) { v0 = phi_f(v0); v1 = phi_f(v1); v2 = phi_f(v2); v3 = phi_f(v3); }
                *reinterpret_cast<uint2*>(dst + crow * 36 + 16 * mt + 4 * g) =
                    make_uint2(rne_pk(v0, v1), rne_pk(v2, v3));
            }
        }

        // ---- GEMM2: KV += phi_k * v^T  (K = this wave's 32 pixels; wave-private LDS)
        #pragma unroll
        for (int h = 0; h < 2; h++) {
            bf16x8 af[2], bv[2];
            #pragma unroll
            for (int mt = 0; mt < 2; mt++)
                af[mt] = lds_read8(kls + (32 * h + 16 * mt + li) * 36 + 8 * g);
            #pragma unroll
            for (int nt = 0; nt < 2; nt++)
                bv[nt] = lds_read8(vls + (32 * h + 16 * nt + li) * 36 + 8 * g);
            #pragma unroll
            for (int mt = 0; mt < 2; mt++)
                #pragma unroll
                for (int nt = 0; nt < 2; nt++)
                    kvacc[h][mt][nt] = MFMA(af[mt], bv[nt], kvacc[h][mt][nt]);
        }
        __syncthreads();   // protect xls before next stage (also pre-reduce barrier on last iter)
    }

    // ---- block reduce (4 waves hold identical KV coverage), store partial slice
    float* rbuf = (float*)smem;  // [4][2048] f32 = 32KB, overlays xls/kls (all reads done)
    #pragma unroll
    for (int h = 0; h < 2; h++)
        #pragma unroll
        for (int mt = 0; mt < 2; mt++)
            #pragma unroll
            for (int nt = 0; nt < 2; nt++) {
                const int t = (h * 2 + mt) * 2 + nt;
                #pragma unroll
                for (int r = 0; r < 4; r++)
                    rbuf[wv * 2048 + t * 256 + (4 * g + r) * 16 + li] = kvacc[h][mt][nt][r];
            }
    __syncthreads();

    float* outp = partials + ((size_t)b * P1_BLOCKS + blockIdx.x) * 2048;
    #pragma unroll
    for (int i = 0; i < 8; i++) {
        const int idx = i * 256 + tid;
        const float sum = rbuf[idx] + rbuf[2048 + idx] + rbuf[4096 + idx] + rbuf[6144 + idx];
        const int t = idx >> 8, within = idx & 255;
        const int row = within >> 4, col = within & 15;
        const int h = t >> 2, mt = (t >> 1) & 1, nt = t & 1;
        outp[(h * 32 + 16 * mt + row) * 32 + 16 * nt + col] = sum;
    }
}

// ---------------- Reduce: kv[b][e] = sum_j partials[b][j][e] ----------------
__global__ __launch_bounds__(256) void la_reduce(
    const float* __restrict__ partials, float* __restrict__ kv)
{
    const int b = blockIdx.x >> 3;
    const int e = (blockIdx.x & 7) * 256 + threadIdx.x;
    const float* p = partials + (size_t)b * P1_BLOCKS * 2048 + e;
    float s0 = 0.f, s1 = 0.f, s2 = 0.f, s3 = 0.f;
    #pragma unroll 8
    for (int j = 0; j < P1_BLOCKS; j += 4) {
        s0 += p[(size_t)j * 2048];
        s1 += p[(size_t)(j + 1) * 2048];
        s2 += p[(size_t)(j + 2) * 2048];
        s3 += p[(size_t)(j + 3) * 2048];
    }
    kv[(size_t)b * 2048 + e] = (s0 + s1) + (s2 + s3);
}

// ---------------- Pass 2: y = proj * (KV^T * phi(q)), x read from bf16 xT ----------------
// grid (256, 8), block 256. Wave-independent 16-pixel strips, zero barriers.
__global__ __launch_bounds__(256) void la_pass2(
    const unsigned short* __restrict__ xt, const float* __restrict__ qkv_w,
    const float* __restrict__ proj_w, const float* __restrict__ kv,
    float* __restrict__ y)
{
    __shared__ __align__(16) unsigned short sm2[4][2][16][72];  // [wave][q|out][px][ch+pad]

    const int tid  = threadIdx.x;
    const int lane = tid & 63;
    const int wv   = __builtin_amdgcn_readfirstlane(tid >> 6);
    const int b    = blockIdx.y;
    const int g    = lane >> 4;
    const int li   = lane & 15;

    unsigned short* qT = &sm2[wv][0][0][0];
    unsigned short* oT = &sm2[wv][1][0][0];

    // preload A-frags: Wq, proj (row-major [o][c]), KV^T (from [b][h][c][d] f32)
    bf16x8 Aq[4][2], Ap[4][2], Akv[2][2];
    #pragma unroll
    for (int mt = 0; mt < 4; mt++)
        #pragma unroll
        for (int ks = 0; ks < 2; ks++) {
            Aq[mt][ks] = load_w_frag(qkv_w, 16 * mt, 32 * ks, lane);
            Ap[mt][ks] = load_w_frag(proj_w, 16 * mt, 32 * ks, lane);
        }
    const float* kvb = kv + (size_t)b * NHEAD * HDIM * HDIM;
    #pragma unroll
    for (int h = 0; h < 2; h++)
        #pragma unroll
        for (int mtd = 0; mtd < 2; mtd++) {
            float f[8];
            #pragma unroll
            for (int e = 0; e < 8; e++)
                f[e] = kvb[h * 1024 + (8 * g + e) * 32 + 16 * mtd + li];  // KV^T[d][c]=KV[c][d]
            Akv[h][mtd] = pack8(f);
        }

    const unsigned short* xtb = xt + (size_t)b * NPIX * CH;
    float*                yb  = y  + (size_t)b * CH * NPIX;

    for (int s = blockIdx.x * 4 + wv; s < 4096; s += 1024) {
        const int px0 = s * 16;

        // ---- B-frags of x from xT: one b128 per ks (8 consecutive channels)
        bf16x8 bx[2];
        const unsigned short* xp = xtb + (size_t)(px0 + li) * CH + 8 * g;
        #pragma unroll
        for (int ks = 0; ks < 2; ks++)
            bx[ks] = *reinterpret_cast<const bf16x8*>(xp + 32 * ks);

        // ---- q = Wq * X, phi, packed store to qT[px][c]
        #pragma unroll
        for (int mt = 0; mt < 4; mt++) {
            f32x4 acc = (f32x4){0.f, 0.f, 0.f, 0.f};
            acc = MFMA(Aq[mt][0], bx[0], acc);
            acc = MFMA(Aq[mt][1], bx[1], acc);
            const float p0 = phi_f(acc[0]), p1 = phi_f(acc[1]);
            const float p2 = phi_f(acc[2]), p3 = phi_f(acc[3]);
            *reinterpret_cast<uint2*>(qT + li * 72 + 16 * mt + 4 * g) =
                make_uint2(rne_pk(p0, p1), rne_pk(p2, p3));
        }

        // ---- out = KV^T * q_phi per head, packed store to oT[px][32h+d]
        #pragma unroll
        for (int h = 0; h < 2; h++) {
            const bf16x8 bq = *reinterpret_cast<const bf16x8*>(qT + li * 72 + 32 * h + 8 * g);
            #pragma unroll
            for (int mtd = 0; mtd < 2; mtd++) {
                f32x4 acc = (f32x4){0.f, 0.f, 0.f, 0.f};
                acc = MFMA(Akv[h][mtd], bq, acc);
                *reinterpret_cast<uint2*>(oT + li * 72 + 32 * h + 16 * mtd + 4 * g) =
                    make_uint2(rne_pk(acc[0], acc[1]), rne_pk(acc[2], acc[3]));
            }
        }

        // ---- y = proj * out, store f32
        const bf16x8 bo0 = *reinterpret_cast<const bf16x8*>(oT + li * 72 + 8 * g);
        const bf16x8 bo1 = *reinterpret_cast<const bf16x8*>(oT + li * 72 + 32 + 8 * g);
        #pragma unroll
        for (int mt = 0; mt < 4; mt++) {
            f32x4 acc = (f32x4){0.f, 0.f, 0.f, 0.f};
            acc = MFMA(Ap[mt][0], bo0, acc);
            acc = MFMA(Ap[mt][1], bo1, acc);
            #pragma unroll
            for (int r = 0; r < 4; r++)
                yb[(size_t)(16 * mt + 4 * g + r) * NPIX + px0 + li] = acc[r];
        }
    }
}

extern "C" void kernel_launch(void* const* d_in, const int* in_sizes, int n_in,
                              void* d_out, int out_size, void* d_ws, size_t ws_size,
                              hipStream_t stream) {
    (void)in_sizes; (void)n_in; (void)out_size; (void)ws_size;
    const float* x      = (const float*)d_in[0];
    const float* qkv_w  = (const float*)d_in[1];
    const float* proj_w = (const float*)d_in[2];
    float* yout = (float*)d_out;

    // ws layout: xT bf16 [8][65536][64] (64 MB), partials [8][P1_BLOCKS][2048] f32 (8 MB), kv (64 KB)
    unsigned short* xt       = (unsigned short*)d_ws;
    float*          partials = (float*)(xt + (size_t)BATCH * NPIX * CH);
    float*          kv       = partials + (size_t)BATCH * P1_BLOCKS * 2048;

    la_pass1 <<<dim3(P1_BLOCKS, BATCH), dim3(256), 0, stream>>>(x, qkv_w, partials, xt);
    la_reduce<<<dim3(64),               dim3(256), 0, stream>>>(partials, kv);
    la_pass2 <<<dim3(256, BATCH),       dim3(256), 0, stream>>>(xt, qkv_w, proj_w, kv, yout);
}

// Round 8
// 116.844 us; speedup vs baseline: 1.2813x; 1.2813x over previous
//
#include <hip/hip_runtime.h>
#include <hip/hip_bf16.h>

#define BATCH 8
#define CH    64
#define NPIX  65536
#define NHEAD 2
#define HDIM  32
#define P1_BLOCKS 128  // pass-1 blocks per batch (partial-KV slices)

typedef __attribute__((ext_vector_type(8))) short bf16x8;
typedef __attribute__((ext_vector_type(4))) float f32x4;

#define MFMA(a, b, c) __builtin_amdgcn_mfma_f32_16x16x32_bf16(a, b, c, 0, 0, 0)

// pack two f32 -> one u32 holding two bf16 (RNE)
__device__ __forceinline__ unsigned rne_pk(float lo, float hi) {
    unsigned ua = __float_as_uint(lo); ua += 0x7fffu + ((ua >> 16) & 1u);
    unsigned ub = __float_as_uint(hi); ub += 0x7fffu + ((ub >> 16) & 1u);
    return (ua >> 16) | (ub & 0xffff0000u);
}

__device__ __forceinline__ bf16x8 pack8(const float* f) {
    int4 iv;
    iv.x = (int)rne_pk(f[0], f[1]);
    iv.y = (int)rne_pk(f[2], f[3]);
    iv.z = (int)rne_pk(f[4], f[5]);
    iv.w = (int)rne_pk(f[6], f[7]);
    return *reinterpret_cast<bf16x8*>(&iv);
}

__device__ __forceinline__ float phi_f(float t) {
    return t > 0.0f ? t + 1.0f : __expf(t);
}

// 8 bf16 from LDS at 8B alignment (two b64 reads)
__device__ __forceinline__ bf16x8 lds_read8(const unsigned short* p) {
    uint2 a = *reinterpret_cast<const uint2*>(p);
    uint2 b = *reinterpret_cast<const uint2*>(p + 4);
    int4 iv; iv.x = (int)a.x; iv.y = (int)a.y; iv.z = (int)b.x; iv.w = (int)b.y;
    return *reinterpret_cast<bf16x8*>(&iv);
}

// A-layout fragment of row-major W[*][64]: lane gets (m = r0+l%16, k = k0+(l/16)*8+e)
// (identical lane data also serves as the B-frag of W^T)
__device__ __forceinline__ bf16x8 load_w_frag(const float* W, int r0, int k0, int lane) {
    const float* p = W + (size_t)(r0 + (lane & 15)) * 64 + k0 + ((lane >> 4) << 3);
    float f[8];
    #pragma unroll
    for (int e = 0; e < 8; e++) f[e] = p[e];
    return pack8(f);
}

// ---------------- Pass 1: partial KV[b][blk][h][c][d] = sum_{n in blk} phi(k) v ----------------
// grid (P1_BLOCKS, 8) = 1024 blocks = exactly 4 blocks/CU; LDS 36864B -> 4 fit; 16 waves/CU.
__global__ __launch_bounds__(256) void la_pass1(
    const float* __restrict__ x, const float* __restrict__ qkv_w,
    float* __restrict__ partials)
{
    __shared__ __align__(16) unsigned char smem[36864];

    const int tid  = threadIdx.x;
    const int lane = tid & 63;
    const int wv   = __builtin_amdgcn_readfirstlane(tid >> 6);
    const int b    = blockIdx.y;
    const int g    = lane >> 4;      // 0..3
    const int li   = lane & 15;

    // wave-private LDS: kls[64][36], vls[64][36] bf16 (row = channel, col = pixel; 72B rows)
    unsigned short* kls = (unsigned short*)(smem + wv * 9216);
    unsigned short* vls = kls + 64 * 36;

    // preload W^T B-frags for k|v output channels (qkv_w rows 64..191)
    bf16x8 Wf[8][2];
    #pragma unroll
    for (int j = 0; j < 8; j++)
        #pragma unroll
        for (int ks = 0; ks < 2; ks++)
            Wf[j][ks] = load_w_frag(qkv_w, 64 + 16 * j, 32 * ks, lane);

    f32x4 kvacc[2][2][2];  // [head][c-tile][d-tile]
    #pragma unroll
    for (int h = 0; h < 2; h++)
        #pragma unroll
        for (int mt = 0; mt < 2; mt++)
            #pragma unroll
            for (int nt = 0; nt < 2; nt++)
                kvacc[h][mt][nt] = (f32x4){0.f, 0.f, 0.f, 0.f};

    const float* xb = x + (size_t)b * CH * NPIX;

    for (int s = blockIdx.x * 4 + wv; s < 2048; s += P1_BLOCKS * 4) {
        const int px0 = s * 32;

        // ---- A-frags of X^T: (m = pixel, k = channel) gathered from global (L3-resident x)
        bf16x8 xa[2][2];
        #pragma unroll
        for (int mt = 0; mt < 2; mt++) {
            const float* xp = xb + px0 + 16 * mt + li;
            #pragma unroll
            for (int ks = 0; ks < 2; ks++) {
                float f[8];
                #pragma unroll
                for (int e = 0; e < 8; e++)
                    f[e] = xp[(size_t)(32 * ks + 8 * g + e) * NPIX];
                xa[mt][ks] = pack8(f);
            }
        }

        // ---- GEMM1: (K|V)^T tiles = X^T * W^T; write packed [c][px] bf16 to kls/vls
        #pragma unroll
        for (int j = 0; j < 8; j++) {
            unsigned short* dst = (j < 4) ? kls : vls;
            const int crow = (j & 3) * 16 + li;
            #pragma unroll
            for (int mt = 0; mt < 2; mt++) {
                f32x4 acc = (f32x4){0.f, 0.f, 0.f, 0.f};
                acc = MFMA(xa[mt][0], Wf[j][0], acc);
                acc = MFMA(xa[mt][1], Wf[j][1], acc);
                float v0 = acc[0], v1 = acc[1], v2 = acc[2], v3 = acc[3];
                if (j < 4) { v0 = phi_f(v0); v1 = phi_f(v1); v2 = phi_f(v2); v3 = phi_f(v3); }
                *reinterpret_cast<uint2*>(dst + crow * 36 + 16 * mt + 4 * g) =
                    make_uint2(rne_pk(v0, v1), rne_pk(v2, v3));
            }
        }

        // ---- GEMM2: KV += phi_k * v^T  (K = 32 pixels of this strip; wave-private LDS)
        #pragma unroll
        for (int h = 0; h < 2; h++) {
            bf16x8 af[2], bv[2];
            #pragma unroll
            for (int mt = 0; mt < 2; mt++)
                af[mt] = lds_read8(kls + (32 * h + 16 * mt + li) * 36 + 8 * g);
            #pragma unroll
            for (int nt = 0; nt < 2; nt++)
                bv[nt] = lds_read8(vls + (32 * h + 16 * nt + li) * 36 + 8 * g);
            #pragma unroll
            for (int mt = 0; mt < 2; mt++)
                #pragma unroll
                for (int nt = 0; nt < 2; nt++)
                    kvacc[h][mt][nt] = MFMA(af[mt], bv[nt], kvacc[h][mt][nt]);
        }
    }

    // ---- block reduce (4 waves hold identical KV coverage), then plain store of the partial
    __syncthreads();
    float* rbuf = (float*)smem;  // [4][2048] f32 = 32KB, overlays kls/vls (all reads done)
    #pragma unroll
    for (int h = 0; h < 2; h++)
        #pragma unroll
        for (int mt = 0; mt < 2; mt++)
            #pragma unroll
            for (int nt = 0; nt < 2; nt++) {
                const int t = (h * 2 + mt) * 2 + nt;
                #pragma unroll
                for (int r = 0; r < 4; r++)
                    rbuf[wv * 2048 + t * 256 + (4 * g + r) * 16 + li] = kvacc[h][mt][nt][r];
            }
    __syncthreads();

    float* outp = partials + ((size_t)b * P1_BLOCKS + blockIdx.x) * 2048;
    #pragma unroll
    for (int i = 0; i < 8; i++) {
        const int idx = i * 256 + tid;
        const float sum = rbuf[idx] + rbuf[2048 + idx] + rbuf[4096 + idx] + rbuf[6144 + idx];
        const int t = idx >> 8, within = idx & 255;
        const int row = within >> 4, col = within & 15;
        const int h = t >> 2, mt = (t >> 1) & 1, nt = t & 1;
        outp[(h * 32 + 16 * mt + row) * 32 + 16 * nt + col] = sum;
    }
}

// ---------------- Reduce: kv[b][e] = sum_j partials[b][j][e] ----------------
__global__ __launch_bounds__(256) void la_reduce(
    const float* __restrict__ partials, float* __restrict__ kv)
{
    const int b = blockIdx.x >> 3;
    const int e = (blockIdx.x & 7) * 256 + threadIdx.x;
    const float* p = partials + (size_t)b * P1_BLOCKS * 2048 + e;
    float s0 = 0.f, s1 = 0.f, s2 = 0.f, s3 = 0.f;
    #pragma unroll 8
    for (int j = 0; j < P1_BLOCKS; j += 4) {
        s0 += p[(size_t)j * 2048];
        s1 += p[(size_t)(j + 1) * 2048];
        s2 += p[(size_t)(j + 2) * 2048];
        s3 += p[(size_t)(j + 3) * 2048];
    }
    kv[(size_t)b * 2048 + e] = (s0 + s1) + (s2 + s3);
}

// ---------------- Pass 2: y = proj * (KV^T * phi(q)), NT stores keep y out of L3 ----------------
// grid (256, 8), block 256, zero barriers.
__global__ __launch_bounds__(256) void la_pass2(
    const float* __restrict__ x, const float* __restrict__ qkv_w,
    const float* __restrict__ proj_w, const float* __restrict__ kv,
    float* __restrict__ y)
{
    __shared__ __align__(16) unsigned short sm2[4][2][16][72];  // [wave][q|out][px][ch+pad]

    const int tid  = threadIdx.x;
    const int lane = tid & 63;
    const int wv   = __builtin_amdgcn_readfirstlane(tid >> 6);
    const int b    = blockIdx.y;
    const int g    = lane >> 4;
    const int li   = lane & 15;

    unsigned short* qT = &sm2[wv][0][0][0];
    unsigned short* oT = &sm2[wv][1][0][0];

    // preload A-frags: Wq, proj (row-major [o][c]), KV^T (from [b][h][c][d] f32)
    bf16x8 Aq[4][2], Ap[4][2], Akv[2][2];
    #pragma unroll
    for (int mt = 0; mt < 4; mt++)
        #pragma unroll
        for (int ks = 0; ks < 2; ks++) {
            Aq[mt][ks] = load_w_frag(qkv_w, 16 * mt, 32 * ks, lane);
            Ap[mt][ks] = load_w_frag(proj_w, 16 * mt, 32 * ks, lane);
        }
    const float* kvb = kv + (size_t)b * NHEAD * HDIM * HDIM;
    #pragma unroll
    for (int h = 0; h < 2; h++)
        #pragma unroll
        for (int mtd = 0; mtd < 2; mtd++) {
            float f[8];
            #pragma unroll
            for (int e = 0; e < 8; e++)
                f[e] = kvb[h * 1024 + (8 * g + e) * 32 + 16 * mtd + li];  // KV^T[d][c]=KV[c][d]
            Akv[h][mtd] = pack8(f);
        }

    const float* xb = x + (size_t)b * CH * NPIX;
    float*       yb = y + (size_t)b * CH * NPIX;

    for (int s = blockIdx.x * 4 + wv; s < 4096; s += 1024) {
        const int px0 = s * 16;

        // ---- B-frags of x: (k = channel, n = pixel) gathered from global (L3-resident x)
        bf16x8 bx[2];
        const float* xp = xb + px0 + li;
        #pragma unroll
        for (int ks = 0; ks < 2; ks++) {
            float f[8];
            #pragma unroll
            for (int e = 0; e < 8; e++)
                f[e] = xp[(size_t)(32 * ks + 8 * g + e) * NPIX];
            bx[ks] = pack8(f);
        }

        // ---- q = Wq * X, phi, packed store to qT[px][c]
        #pragma unroll
        for (int mt = 0; mt < 4; mt++) {
            f32x4 acc = (f32x4){0.f, 0.f, 0.f, 0.f};
            acc = MFMA(Aq[mt][0], bx[0], acc);
            acc = MFMA(Aq[mt][1], bx[1], acc);
            const float p0 = phi_f(acc[0]), p1 = phi_f(acc[1]);
            const float p2 = phi_f(acc[2]), p3 = phi_f(acc[3]);
            *reinterpret_cast<uint2*>(qT + li * 72 + 16 * mt + 4 * g) =
                make_uint2(rne_pk(p0, p1), rne_pk(p2, p3));
        }

        // ---- out = KV^T * q_phi per head, packed store to oT[px][32h+d]
        #pragma unroll
        for (int h = 0; h < 2; h++) {
            const bf16x8 bq = *reinterpret_cast<const bf16x8*>(qT + li * 72 + 32 * h + 8 * g);
            #pragma unroll
            for (int mtd = 0; mtd < 2; mtd++) {
                f32x4 acc = (f32x4){0.f, 0.f, 0.f, 0.f};
                acc = MFMA(Akv[h][mtd], bq, acc);
                *reinterpret_cast<uint2*>(oT + li * 72 + 32 * h + 16 * mtd + 4 * g) =
                    make_uint2(rne_pk(acc[0], acc[1]), rne_pk(acc[2], acc[3]));
            }
        }

        // ---- y = proj * out, nontemporal f32 stores (bypass L3: keep x resident)
        const bf16x8 bo0 = *reinterpret_cast<const bf16x8*>(oT + li * 72 + 8 * g);
        const bf16x8 bo1 = *reinterpret_cast<const bf16x8*>(oT + li * 72 + 32 + 8 * g);
        #pragma unroll
        for (int mt = 0; mt < 4; mt++) {
            f32x4 acc = (f32x4){0.f, 0.f, 0.f, 0.f};
            acc = MFMA(Ap[mt][0], bo0, acc);
            acc = MFMA(Ap[mt][1], bo1, acc);
            #pragma unroll
            for (int r = 0; r < 4; r++)
                __builtin_nontemporal_store(acc[r],
                    &yb[(size_t)(16 * mt + 4 * g + r) * NPIX + px0 + li]);
        }
    }
}

extern "C" void kernel_launch(void* const* d_in, const int* in_sizes, int n_in,
                              void* d_out, int out_size, void* d_ws, size_t ws_size,
                              hipStream_t stream) {
    (void)in_sizes; (void)n_in; (void)out_size; (void)ws_size;
    const float* x      = (const float*)d_in[0];
    const float* qkv_w  = (const float*)d_in[1];
    const float* proj_w = (const float*)d_in[2];
    float* yout = (float*)d_out;

    // ws layout: partials [8][P1_BLOCKS][2048] f32 (8 MB), then final kv [8][2048] f32 (64 KB)
    float* partials = (float*)d_ws;
    float* kv       = partials + (size_t)BATCH * P1_BLOCKS * 2048;

    la_pass1 <<<dim3(P1_BLOCKS, BATCH), dim3(256), 0, stream>>>(x, qkv_w, partials);
    la_reduce<<<dim3(64),               dim3(256), 0, stream>>>(partials, kv);
    la_pass2 <<<dim3(256, BATCH),       dim3(256), 0, stream>>>(x, qkv_w, proj_w, kv, yout);
}